// Round 12
// baseline (200.482 us; speedup 1.0000x reference)
//
#include <hip/hip_runtime.h>

// Boundary_binaryLoss: 15x15 binary morphology boundary mask + masked NLL mean.
// B=32, C=2, H=480, W=864. logits [B,C,H,W] f32, labels [B,H,W] i32 in {0,1,255}.
//
// valid(b,h,w) = (label != 255) && (clipped 15x15 window has a px with
//   np_label==0 (label 0 or 255) AND a px with np_label==255 (label 1))
// loss = -sum(valid ? logits[b,label,h,w] : 0) / max(#valid, 1)
//
// History: R1-R5 structural fixes -> 63-66us plateau. R6 (fat fused,
//   barrier-free) = 63us best. R7 starved(103). R8 block-coop(69).
//   R9 +XCD swizzle: FETCH 122->78MB, dur unchanged. R10/R11 byte cuts
//   killed by spill. R12 spill-free min-bytes (205MB, WRITE 120B, VGPR 84):
//   STILL 63.4us -- the effective service rate DROPPED to 3.2TB/s (R11's
//   spilled 449MB ran at 4.5). Every spill-free config >=3.8k waves lands
//   at 63-66us regardless of bytes (205-292MB). The common factor: every
//   wave is a latency-chained label-halo + logits mix. The machine services
//   pure streams at 6.6TB/s (harness fill kernel: 415MB/64us).
// R13: SEPARABLE TWO-PASS -- eliminate the halo instead of amortizing it.
//   Pass1: labels once (57MB, no v-halo), h-OR via proven shuffles, write
//     4b/px plane (h-flags|center) = 6.6MB. Pure stream.
//   Pass2: R12 verbatim except phase1 reads 30 ushort flag rows (12.4MB)
//     instead of 30 int4 label rows; no shuffles. Logits pipeline untouched.
//     XCD swizzles aligned so pass2 hits pass1's flags in XCD-local L2.
//   Total ~182MB, ~90% in clean streams. ws needs 6.7MB -> guarded fallback
//   to monolithic R12 if ws_size too small.
//   Predict: pass1 10-14us (WRITE ~6.6MB), pass2 30-40us, combined 40-54
//   vs 63. Tripwires: pass2 WRITE ~60KB, VGPR <= 84. If combined >= 60us:
//   declare the empirical wall next round.

namespace {
constexpr int B_ = 32;
constexpr int H_ = 480;
constexpr int W_ = 864;
constexpr int HW = H_ * W_;
constexpr int R_ = 7;
constexpr int TH_ = 16;                   // pass2 output rows per wave
constexpr int LH = TH_ + 2 * R_;          // 30 flag rows read in pass2
constexpr int SW = 216;                   // output cols per strip
constexpr int NSX = W_ / SW;              // 4
constexpr int NSY = H_ / TH_;             // 30
constexpr int NBLK = B_ * NSX * NSY;      // 3840 pass2 blocks (%8==0)
constexpr int X4 = W_ / 4;                // 216 ushorts per flag row
constexpr int RG = H_ / 16;               // 30 rowgroups in pass1
constexpr int NB1 = B_ * RG;              // 960 pass1 blocks (%8==0)
constexpr size_t FLAG_OFF = 61440;        // partials (3840*16B) first
constexpr size_t FLAG_BYTES = (size_t)B_ * H_ * X4 * 2;  // 6,635,520
constexpr size_t WS_NEED = FLAG_OFF + FLAG_BYTES;
} // namespace

typedef unsigned long long u64;

__device__ __forceinline__ u64 shfl_up64(u64 x, int d) {
  return __shfl_up(x, d, 64);
}
__device__ __forceinline__ u64 shfl_dn64(u64 x, int d) {
  return __shfl_down(x, d, 64);
}

// ===================== pass 1: labels -> h-OR'd 4b/px flags ================
// nibble per px: bit0 np==0 in 15-col window, bit1 np==255 in window,
//                bit2 label==1 (chan), bit3 label==255 (ignore)
extern "C" __global__ __launch_bounds__(256, 2)
void boundary_pass1(const int* __restrict__ labels,
                    unsigned short* __restrict__ flags)
{
  const int tid = threadIdx.x;
  const int lane = tid & 63;
  const int wv = tid >> 6;                  // strip 0..3
  // XCD swizzle aligned with pass2: XCD k gets img [4k, 4k+4).
  const int lb = (blockIdx.x & 7) * (NB1 / 8) + (blockIdx.x >> 3);
  const int img = lb / RG;
  const int rg = lb - img * RG;
  const int y0 = rg * 16;                   // rows [y0, y0+16) all in-image
  const int strip = wv;

  const int cb0 = strip * SW - 8 + 4 * lane;
  const bool colinb = (cb0 >= 0) && (cb0 + 3 < W_);
  const int cbc = colinb ? cb0 : (cb0 < 0 ? 0 : W_ - 4);
  const bool labok = colinb && (lane < 58);
  const bool outl = (lane >= 2) && (lane < 56);
  const int* __restrict__ lab = labels + img * HW + cbc;

  // fused load+fold: 16 int4 rows -> 2b/row f (window src) + 2b/row c
  unsigned f0 = 0, f1 = 0, f2 = 0, f3 = 0;
  unsigned c0 = 0, c1 = 0, c2 = 0, c3 = 0;
#pragma unroll
  for (int a = 0; a < 16; ++a) {
    const int4 v = *(const int4*)(lab + (size_t)(y0 + a) * W_);
    const unsigned m = labok ? 3u : 0u;
    const int sh = 2 * a;
    f0 |= (((v.x == 1) ? 2u : 1u) & m) << sh;
    f1 |= (((v.y == 1) ? 2u : 1u) & m) << sh;
    f2 |= (((v.z == 1) ? 2u : 1u) & m) << sh;
    f3 |= (((v.w == 1) ? 2u : 1u) & m) << sh;
    c0 |= (((v.x == 1) ? 1u : 0u) | ((v.x == 255) ? 2u : 0u)) << sh;
    c1 |= (((v.y == 1) ? 1u : 0u) | ((v.y == 255) ? 2u : 0u)) << sh;
    c2 |= (((v.z == 1) ? 1u : 0u) | ((v.z == 255) ? 2u : 0u)) << sh;
    c3 |= (((v.w == 1) ? 1u : 0u) | ((v.w == 255) ? 2u : 0u)) << sh;
  }

  // horizontal 15-OR (R6-proven, 32-bit): garbage confined outside [2,56)
  const unsigned allf = f0 | f1 | f2 | f3;
  const unsigned s2 = f2 | f3, s3 = f1 | s2;
  const unsigned p2 = f0 | f1, p3 = p2 | f2;
  const unsigned core = __shfl_up(allf, 1, 64) | allf | __shfl_down(allf, 1, 64);
  const unsigned w0 = core | __shfl_up(s3, 2, 64);
  const unsigned w1 = core | __shfl_up(s2, 2, 64) | __shfl_down(f0, 2, 64);
  const unsigned w2 = core | __shfl_up(f3, 2, 64) | __shfl_down(p2, 2, 64);
  const unsigned w3 = core | __shfl_down(p3, 2, 64);

  if (outl) {
    unsigned short* fp =
        flags + ((size_t)img * H_ + y0) * X4 + strip * 54 + (lane - 2);
#pragma unroll
    for (int a = 0; a < 16; ++a) {
      const int sh = 2 * a;
      const unsigned n0 = ((w0 >> sh) & 3u) | (((c0 >> sh) & 3u) << 2);
      const unsigned n1 = ((w1 >> sh) & 3u) | (((c1 >> sh) & 3u) << 2);
      const unsigned n2 = ((w2 >> sh) & 3u) | (((c2 >> sh) & 3u) << 2);
      const unsigned n3 = ((w3 >> sh) & 3u) | (((c3 >> sh) & 3u) << 2);
      fp[(size_t)a * X4] =
          (unsigned short)(n0 | (n1 << 4) | (n2 << 8) | (n3 << 12));
    }
  }
}

// ============ pass 2: flags (v-OR) + logits gather + reduce ===============
extern "C" __global__ __launch_bounds__(64, 2)
void boundary_pass2(const float* __restrict__ logits,
                    const unsigned short* __restrict__ flags,
                    double2* __restrict__ partials)
{
  const int lane = threadIdx.x;             // one wave per block
  const int bid = blockIdx.x;
  const int lb = (bid & 7) * (NBLK / 8) + (bid >> 3);
  const int img = lb / (NSX * NSY);
  const int r = lb - img * (NSX * NSY);
  const int strip = r / NSY;
  const int seg = r - strip * NSY;
  const int gr0 = seg * TH_;

  const int cb0 = strip * SW - 8 + 4 * lane;
  const bool outl = (lane >= 2) && (lane < 56);
  const float* __restrict__ lg = logits + (size_t)(2 * img) * HW;
  const float* pg = lg + (size_t)gr0 * W_ + cb0;     // deref'd only if outl

  // ---- phase 1: 30 ushort flag rows -> f (2b/row window src, u64) and
  //      cp (2b/output-row center). No shuffles needed (h-OR precomputed).
  u64 f0 = 0, f1 = 0, f2 = 0, f3 = 0;
  unsigned cp0 = 0, cp1 = 0, cp2 = 0, cp3 = 0;
  if (outl) {
    const unsigned short* fp =
        flags + (size_t)img * H_ * X4 + strip * 54 + (lane - 2);
#pragma unroll
    for (int a = 0; a < LH; ++a) {
      int gr = gr0 - R_ + a;
      gr = gr < 0 ? 0 : (gr >= H_ ? H_ - 1 : gr);    // clamped; masked below
      const unsigned t = fp[(size_t)gr * X4];
      f0 |= (u64)(t & 3u) << (2 * a);
      f1 |= (u64)((t >> 4) & 3u) << (2 * a);
      f2 |= (u64)((t >> 8) & 3u) << (2 * a);
      f3 |= (u64)((t >> 12) & 3u) << (2 * a);
      if (a >= R_ && a < R_ + TH_) {
        const int sh = 2 * (a - R_);
        cp0 |= ((t >> 2) & 3u) << sh;
        cp1 |= ((t >> 6) & 3u) << sh;
        cp2 |= ((t >> 10) & 3u) << sh;
        cp3 |= ((t >> 14) & 3u) << sh;
      }
    }
    // clip OOB image rows
    const int tv = gr0 == 0 ? R_ : 0;
    const int hi = LH < (H_ + R_ - gr0) ? LH : (H_ + R_ - gr0);
    u64 rm = (2 * (hi - tv) >= 32)
                 ? ((((1ull << (2 * (hi - tv) - 32)) - 1ull) << 32) | 0xFFFFFFFFull)
                 : ((1ull << (2 * (hi - tv))) - 1ull);
    rm <<= 2 * tv;
    f0 &= rm; f1 &= rm; f2 &= rm; f3 &= rm;
  }

  // ---- logits quarter-tile machinery (R12-proven, spill-free) ----
  float4 qa0[4], qa1[4], qb0[4], qb1[4];
#define ISSUE(G0, G1, q)                                                    \
  if (outl) {                                                               \
    const float* p_ = pg + (size_t)(4 * (q)) * W_;                          \
    _Pragma("unroll") for (int o = 0; o < 4; ++o) {                         \
      G0[o] = *(const float4*)(p_ + (size_t)o * W_);                        \
      G1[o] = *(const float4*)(p_ + (size_t)o * W_ + HW);                   \
    }                                                                       \
  }
  ISSUE(qa0, qa1, 0)

  // ---- vertical 15-OR (bit 2o = OR flag rows o..o+14, o = 0..15) ----
  f0 |= f0 >> 2;  f0 |= f0 >> 4;  f0 |= f0 >> 8;  f0 |= f0 >> 14;
  f1 |= f1 >> 2;  f1 |= f1 >> 4;  f1 |= f1 >> 8;  f1 |= f1 >> 14;
  f2 |= f2 >> 2;  f2 |= f2 >> 4;  f2 |= f2 >> 8;  f2 |= f2 >> 14;
  f3 |= f3 >> 2;  f3 |= f3 >> 4;  f3 |= f3 >> 8;  f3 |= f3 >> 14;

  double lsum = 0.0;
  unsigned lcnt = 0;
#define CONSUME(G0, G1, q)                                                  \
  if (outl) {                                                               \
    _Pragma("unroll") for (int o = 0; o < 4; ++o) {                         \
      const int ro = 4 * (q) + o;                                           \
      const unsigned b0 = (unsigned)(f0 >> (2 * ro)) & 3u;                  \
      const unsigned b1 = (unsigned)(f1 >> (2 * ro)) & 3u;                  \
      const unsigned b2 = (unsigned)(f2 >> (2 * ro)) & 3u;                  \
      const unsigned b3 = (unsigned)(f3 >> (2 * ro)) & 3u;                  \
      const unsigned q0 = (cp0 >> (2 * ro)) & 3u;                           \
      const unsigned q1 = (cp1 >> (2 * ro)) & 3u;                           \
      const unsigned q2 = (cp2 >> (2 * ro)) & 3u;                           \
      const unsigned q3 = (cp3 >> (2 * ro)) & 3u;                           \
      const float4 a = G0[o], c = G1[o];                                    \
      const bool k0 = (b0 == 3u) && !(q0 & 2u);                             \
      const bool k1 = (b1 == 3u) && !(q1 & 2u);                             \
      const bool k2 = (b2 == 3u) && !(q2 & 2u);                             \
      const bool k3 = (b3 == 3u) && !(q3 & 2u);                             \
      lsum += k0 ? (double)((q0 & 1u) ? c.x : a.x) : 0.0;                   \
      lsum += k1 ? (double)((q1 & 1u) ? c.y : a.y) : 0.0;                   \
      lsum += k2 ? (double)((q2 & 1u) ? c.z : a.z) : 0.0;                   \
      lsum += k3 ? (double)((q3 & 1u) ? c.w : a.w) : 0.0;                   \
      lcnt += (unsigned)k0 + k1 + k2 + k3;                                  \
    }                                                                       \
  }
  ISSUE(qb0, qb1, 1)
  CONSUME(qa0, qa1, 0)
  __builtin_amdgcn_sched_barrier(0);
  ISSUE(qa0, qa1, 2)
  CONSUME(qb0, qb1, 1)
  __builtin_amdgcn_sched_barrier(0);
  ISSUE(qb0, qb1, 3)
  CONSUME(qa0, qa1, 2)
  __builtin_amdgcn_sched_barrier(0);
  CONSUME(qb0, qb1, 3)
#undef ISSUE
#undef CONSUME

#pragma unroll
  for (int off = 32; off > 0; off >>= 1) {
    lsum += __shfl_down(lsum, off, 64);
    lcnt += __shfl_down(lcnt, off, 64);
  }
  if (lane == 0) partials[bid] = make_double2(lsum, (double)lcnt);
}

// ====== monolithic fallback (R12 verbatim) if ws too small for flags ======
extern "C" __global__ __launch_bounds__(64, 2)
void boundary_loss_mono(const float* __restrict__ logits,
                        const int* __restrict__ labels,
                        double2* __restrict__ partials)
{
  const int lane = threadIdx.x;
  const int bid = blockIdx.x;
  const int lb = (bid & 7) * (NBLK / 8) + (bid >> 3);
  const int img = lb / (NSX * NSY);
  const int r = lb - img * (NSX * NSY);
  const int strip = r / NSY;
  const int seg = r - strip * NSY;
  const int gr0 = seg * TH_;

  const int cb0 = strip * SW - 8 + 4 * lane;
  const bool colinb = (cb0 >= 0) && (cb0 + 3 < W_);
  const int cbc = colinb ? cb0 : (cb0 < 0 ? 0 : W_ - 4);
  const bool labok = colinb && (lane < 58);
  const bool outl = (lane >= 2) && (lane < 56);

  const int* __restrict__ lab = labels + img * HW + cbc;
  const float* __restrict__ lg = logits + (size_t)(2 * img) * HW;
  const float* pg = lg + (size_t)gr0 * W_ + cb0;

  u64 f0 = 0, f1 = 0, f2 = 0, f3 = 0;
  unsigned cp0 = 0, cp1 = 0, cp2 = 0, cp3 = 0;
#pragma unroll
  for (int a = 0; a < LH; ++a) {
    int gr = gr0 - R_ + a;
    gr = gr < 0 ? 0 : (gr >= H_ ? H_ - 1 : gr);
    const int4 v = *(const int4*)(lab + gr * W_);
    const unsigned e1x = (v.x == 1), e1y = (v.y == 1),
                   e1z = (v.z == 1), e1w = (v.w == 1);
    const unsigned m = labok ? 3u : 0u;
    f0 |= (u64)((1u + e1x) & m) << (2 * a);
    f1 |= (u64)((1u + e1y) & m) << (2 * a);
    f2 |= (u64)((1u + e1z) & m) << (2 * a);
    f3 |= (u64)((1u + e1w) & m) << (2 * a);
    if (a >= R_ && a < R_ + TH_) {
      const int sh = 2 * (a - R_);
      cp0 |= (e1x | ((unsigned)(v.x == 255) << 1)) << sh;
      cp1 |= (e1y | ((unsigned)(v.y == 255) << 1)) << sh;
      cp2 |= (e1z | ((unsigned)(v.z == 255) << 1)) << sh;
      cp3 |= (e1w | ((unsigned)(v.w == 255) << 1)) << sh;
    }
  }
  {
    const int tv = gr0 == 0 ? R_ : 0;
    const int hi = LH < (H_ + R_ - gr0) ? LH : (H_ + R_ - gr0);
    u64 rm = (2 * (hi - tv) >= 32)
                 ? ((((1ull << (2 * (hi - tv) - 32)) - 1ull) << 32) | 0xFFFFFFFFull)
                 : ((1ull << (2 * (hi - tv))) - 1ull);
    rm <<= 2 * tv;
    if (!colinb) rm = 0;
    f0 &= rm; f1 &= rm; f2 &= rm; f3 &= rm;
  }

  float4 qa0[4], qa1[4], qb0[4], qb1[4];
#define ISSUE(G0, G1, q)                                                    \
  if (outl) {                                                               \
    const float* p_ = pg + (size_t)(4 * (q)) * W_;                          \
    _Pragma("unroll") for (int o = 0; o < 4; ++o) {                         \
      G0[o] = *(const float4*)(p_ + (size_t)o * W_);                        \
      G1[o] = *(const float4*)(p_ + (size_t)o * W_ + HW);                   \
    }                                                                       \
  }
  ISSUE(qa0, qa1, 0)

  const u64 allf = f0 | f1 | f2 | f3;
  const u64 s2 = f2 | f3, s3 = f1 | s2;
  const u64 p2 = f0 | f1, p3 = p2 | f2;
  const u64 core = shfl_up64(allf, 1) | allf | shfl_dn64(allf, 1);
  u64 w0 = core | shfl_up64(s3, 2);
  u64 w1 = core | shfl_up64(s2, 2) | shfl_dn64(f0, 2);
  u64 w2 = core | shfl_up64(f3, 2) | shfl_dn64(p2, 2);
  u64 w3 = core | shfl_dn64(p3, 2);
  w0 |= w0 >> 2;  w0 |= w0 >> 4;  w0 |= w0 >> 8;  w0 |= w0 >> 14;
  w1 |= w1 >> 2;  w1 |= w1 >> 4;  w1 |= w1 >> 8;  w1 |= w1 >> 14;
  w2 |= w2 >> 2;  w2 |= w2 >> 4;  w2 |= w2 >> 8;  w2 |= w2 >> 14;
  w3 |= w3 >> 2;  w3 |= w3 >> 4;  w3 |= w3 >> 8;  w3 |= w3 >> 14;

  double lsum = 0.0;
  unsigned lcnt = 0;
#define CONSUME(G0, G1, q)                                                  \
  if (outl) {                                                               \
    _Pragma("unroll") for (int o = 0; o < 4; ++o) {                         \
      const int ro = 4 * (q) + o;                                           \
      const unsigned b0 = (unsigned)(w0 >> (2 * ro)) & 3u;                  \
      const unsigned b1 = (unsigned)(w1 >> (2 * ro)) & 3u;                  \
      const unsigned b2 = (unsigned)(w2 >> (2 * ro)) & 3u;                  \
      const unsigned b3 = (unsigned)(w3 >> (2 * ro)) & 3u;                  \
      const unsigned q0 = (cp0 >> (2 * ro)) & 3u;                           \
      const unsigned q1 = (cp1 >> (2 * ro)) & 3u;                           \
      const unsigned q2 = (cp2 >> (2 * ro)) & 3u;                           \
      const unsigned q3 = (cp3 >> (2 * ro)) & 3u;                           \
      const float4 a = G0[o], c = G1[o];                                    \
      const bool k0 = (b0 == 3u) && !(q0 & 2u);                             \
      const bool k1 = (b1 == 3u) && !(q1 & 2u);                             \
      const bool k2 = (b2 == 3u) && !(q2 & 2u);                             \
      const bool k3 = (b3 == 3u) && !(q3 & 2u);                             \
      lsum += k0 ? (double)((q0 & 1u) ? c.x : a.x) : 0.0;                   \
      lsum += k1 ? (double)((q1 & 1u) ? c.y : a.y) : 0.0;                   \
      lsum += k2 ? (double)((q2 & 1u) ? c.z : a.z) : 0.0;                   \
      lsum += k3 ? (double)((q3 & 1u) ? c.w : a.w) : 0.0;                   \
      lcnt += (unsigned)k0 + k1 + k2 + k3;                                  \
    }                                                                       \
  }
  ISSUE(qb0, qb1, 1)
  CONSUME(qa0, qa1, 0)
  __builtin_amdgcn_sched_barrier(0);
  ISSUE(qa0, qa1, 2)
  CONSUME(qb0, qb1, 1)
  __builtin_amdgcn_sched_barrier(0);
  ISSUE(qb0, qb1, 3)
  CONSUME(qa0, qa1, 2)
  __builtin_amdgcn_sched_barrier(0);
  CONSUME(qb0, qb1, 3)
#undef ISSUE
#undef CONSUME

#pragma unroll
  for (int off = 32; off > 0; off >>= 1) {
    lsum += __shfl_down(lsum, off, 64);
    lcnt += __shfl_down(lcnt, off, 64);
  }
  if (lane == 0) partials[bid] = make_double2(lsum, (double)lcnt);
}

extern "C" __global__ __launch_bounds__(1024)
void boundary_loss_final(const double2* __restrict__ partials,
                         float* __restrict__ out)
{
  __shared__ double red_s[16];
  __shared__ double red_c[16];
  const int tid = threadIdx.x;
  double s = 0.0, c = 0.0;
  for (int i = tid; i < NBLK; i += 1024) {
    const double2 p = partials[i];
    s += p.x;
    c += p.y;
  }
#pragma unroll
  for (int off = 32; off > 0; off >>= 1) {
    s += __shfl_down(s, off, 64);
    c += __shfl_down(c, off, 64);
  }
  const int wave = tid >> 6;
  if ((tid & 63) == 0) { red_s[wave] = s; red_c[wave] = c; }
  __syncthreads();
  if (tid == 0) {
    double ts = 0.0, tc = 0.0;
#pragma unroll
    for (int i = 0; i < 16; ++i) { ts += red_s[i]; tc += red_c[i]; }
    if (tc < 1.0) tc = 1.0;
    out[0] = (float)(-ts / tc);
  }
}

extern "C" void kernel_launch(void* const* d_in, const int* in_sizes, int n_in,
                              void* d_out, int out_size, void* d_ws, size_t ws_size,
                              hipStream_t stream)
{
  const float* logits = (const float*)d_in[0];
  const int* labels = (const int*)d_in[1];
  float* out = (float*)d_out;
  double2* partials = (double2*)d_ws;  // 3840*16 B = 61,440 B at offset 0

  if (ws_size >= WS_NEED) {
    unsigned short* flags = (unsigned short*)((char*)d_ws + FLAG_OFF);
    boundary_pass1<<<dim3(NB1), 256, 0, stream>>>(labels, flags);
    boundary_pass2<<<dim3(NBLK), 64, 0, stream>>>(logits, flags, partials);
  } else {
    boundary_loss_mono<<<dim3(NBLK), 64, 0, stream>>>(logits, labels, partials);
  }
  boundary_loss_final<<<1, 1024, 0, stream>>>(partials, out);
}

// Round 13
// 194.920 us; speedup vs baseline: 1.0285x; 1.0285x over previous
//
#include <hip/hip_runtime.h>

// Boundary_binaryLoss: 15x15 binary morphology boundary mask + masked NLL mean.
// B=32, C=2, H=480, W=864. logits [B,C,H,W] f32, labels [B,H,W] i32 in {0,1,255}.
//
// valid(b,h,w) = (label != 255) && (clipped 15x15 window has a px with
//   np_label==0 (label 0 or 255) AND a px with np_label==255 (label 1))
// loss = -sum(valid ? logits[b,label,h,w] : 0) / max(#valid, 1)
//
// FINAL (R14 = R12 restored). 13-round summary:
//   R1-R5 structural fixes -> 63-66us plateau. R6 fat fused barrier-free:
//   63us. R7 TH32 starved: 103. R8 block-coop: 69. R9 +XCD swizzle: FETCH
//   122->78MB, dur unchanged. R10/R11 byte cuts killed by spill. R12
//   spill-free min-bytes (205MB, WRITE 120B, VGPR 84): 63.4us. R13 two-pass
//   pure streams: combined ~76us -- worse (2nd dispatch + flag round-trip
//   cost more than the halo saved).
// STRUCTURAL CONSTRAINT (why ~63us is the wall):
//   Compulsory traffic = 159MB (106 logits + 53 labels, each line touched
//   once by one CU; random 0/1 labels touch both channel planes) + ~1.9x
//   label halo in any one-pass form => ~205MB. R12 services it at
//   12.6 GB/s/CU unique-read rate == the machine's measured float4-copy
//   read-side rate (m13: 6.29 TB/s r+w). Reads are latency x outstanding-
//   request bound; the rate saturates by ~8 waves/CU (R0's 26 waves/CU:
//   identical time). Knobs explored with ZERO effect: bytes 205-292MB,
//   occupancy 21-63%, barriers 0-2, width 4-16B/lane, XCD locality,
//   1-vs-2-pass. The write-only fill's 6.9 TB/s is not reachable for reads.

namespace {
constexpr int B_ = 32;
constexpr int H_ = 480;
constexpr int W_ = 864;
constexpr int HW = H_ * W_;
constexpr int R_ = 7;
constexpr int TH_ = 16;                   // output rows per wave
constexpr int LH = TH_ + 2 * R_;          // 30 label rows
constexpr int SW = 216;                   // output cols per strip
constexpr int NSX = W_ / SW;              // 4
constexpr int NSY = H_ / TH_;             // 30
constexpr int NBLK = B_ * NSX * NSY;      // 3840 single-wave blocks (%8==0)
} // namespace

typedef unsigned long long u64;

__device__ __forceinline__ u64 shfl_up64(u64 x, int d) {
  return __shfl_up(x, d, 64);
}
__device__ __forceinline__ u64 shfl_dn64(u64 x, int d) {
  return __shfl_down(x, d, 64);
}

extern "C" __global__ __launch_bounds__(64, 2)
void boundary_loss_main(const float* __restrict__ logits,
                        const int* __restrict__ labels,
                        double2* __restrict__ partials)
{
  const int lane = threadIdx.x;             // one wave per block
  const int bid = blockIdx.x;
  // XCD swizzle: XCD k owns lb in [480k, 480k+480) = 4 whole images;
  // consecutive lb = vertically adjacent segments (halo rows XCD-local).
  const int lb = (bid & 7) * (NBLK / 8) + (bid >> 3);
  const int img = lb / (NSX * NSY);         // /120
  const int r = lb - img * (NSX * NSY);
  const int strip = r / NSY;                // 0..3
  const int seg = r - strip * NSY;          // 0..29
  const int gr0 = seg * TH_;                // first output row

  const int cb0 = strip * SW - 8 + 4 * lane;          // lane's 4-col base
  const bool colinb = (cb0 >= 0) && (cb0 + 3 < W_);   // W%4==0: all-or-none
  const int cbc = colinb ? cb0 : (cb0 < 0 ? 0 : W_ - 4);
  const bool labok = colinb && (lane < 58);           // 232 halo cols
  const bool outl = (lane >= 2) && (lane < 56);       // 54 lanes x 4 = 216

  const int* __restrict__ lab = labels + img * HW + cbc;
  const float* __restrict__ lg = logits + (size_t)(2 * img) * HW;
  const float* pg = lg + (size_t)gr0 * W_ + cb0;      // deref'd only if outl

  // ---- phase 1: FUSED label load+fold, 30x int4 (~1KB/wave requests).
  // f[j]: 2 bits/label row in ONE u64 (60 bits): bit0 np==0 (label 0/255),
  // bit1 np==255 (label 1). cp[j]: 2 bits/output row (bit0 chan, bit1 ign).
  u64 f0 = 0, f1 = 0, f2 = 0, f3 = 0;
  unsigned cp0 = 0, cp1 = 0, cp2 = 0, cp3 = 0;
#pragma unroll
  for (int a = 0; a < LH; ++a) {
    int gr = gr0 - R_ + a;
    gr = gr < 0 ? 0 : (gr >= H_ ? H_ - 1 : gr);       // clamped; masked below
    const int4 v = *(const int4*)(lab + gr * W_);
    const unsigned e1x = (v.x == 1), e1y = (v.y == 1),
                   e1z = (v.z == 1), e1w = (v.w == 1);
    f0 |= (u64)(1u + e1x) << (2 * a);
    f1 |= (u64)(1u + e1y) << (2 * a);
    f2 |= (u64)(1u + e1z) << (2 * a);
    f3 |= (u64)(1u + e1w) << (2 * a);
    if (a >= R_ && a < R_ + TH_) {
      const int sh = 2 * (a - R_);
      cp0 |= (e1x | ((unsigned)(v.x == 255) << 1)) << sh;
      cp1 |= (e1y | ((unsigned)(v.y == 255) << 1)) << sh;
      cp2 |= (e1z | ((unsigned)(v.z == 255) << 1)) << sh;
      cp3 |= (e1w | ((unsigned)(v.w == 255) << 1)) << sh;
    }
  }
  // clip: OOB image rows / OOB lane columns contribute nothing
  {
    const int tv = gr0 == 0 ? R_ : 0;                   // invalid top rows
    const int hi = LH < (H_ + R_ - gr0) ? LH : (H_ + R_ - gr0);
    u64 rm = (2 * (hi - tv) >= 32)
                 ? ((((1ull << (2 * (hi - tv) - 32)) - 1ull) << 32) | 0xFFFFFFFFull)
                 : ((1ull << (2 * (hi - tv))) - 1ull);
    rm <<= 2 * tv;
    if (!colinb) rm = 0;
    f0 &= rm; f1 &= rm; f2 &= rm; f3 &= rm;
  }

  // ---- logits quarter-tile machinery: 4 rows x 2 ch = 8 float4 = 32 VGPR
  //      per quarter; A/B named buffers, static indexing only ----
  float4 qa0[4], qa1[4], qb0[4], qb1[4];
#define ISSUE(G0, G1, q)                                                    \
  if (outl) {                                                               \
    const float* p_ = pg + (size_t)(4 * (q)) * W_;                          \
    _Pragma("unroll") for (int o = 0; o < 4; ++o) {                         \
      G0[o] = *(const float4*)(p_ + (size_t)o * W_);                        \
      G1[o] = *(const float4*)(p_ + (size_t)o * W_ + HW);                   \
    }                                                                       \
  }

  // issue Q0 now: latency hides under h-OR + v-fold VALU
  ISSUE(qa0, qa1, 0)

  // ---- phase 3: horizontal 15-OR, exact per column over 4-col lanes ----
  // col 4l+0: sfx3(l-2)|all(l-1..l+1)     col 4l+1: sfx2|core|pfx1(l+2)
  // col 4l+2: sfx1|core|pfx2(l+2)         col 4l+3: all(l-1..l+1)|pfx3(l+2)
  // shuffle garbage only reaches lanes outside [2,56) -> never consumed.
  const u64 allf = f0 | f1 | f2 | f3;
  const u64 s2 = f2 | f3, s3 = f1 | s2;
  const u64 p2 = f0 | f1, p3 = p2 | f2;
  const u64 core = shfl_up64(allf, 1) | allf | shfl_dn64(allf, 1);
  u64 w0 = core | shfl_up64(s3, 2);
  u64 w1 = core | shfl_up64(s2, 2) | shfl_dn64(f0, 2);
  u64 w2 = core | shfl_up64(f3, 2) | shfl_dn64(p2, 2);
  u64 w3 = core | shfl_dn64(p3, 2);

  // ---- phase 4: vertical 15-OR (bit 2o = OR label rows o..o+14, o=0..15;
  //      max source bit 2*15+28 = 58 < 64) ----
  w0 |= w0 >> 2;  w0 |= w0 >> 4;  w0 |= w0 >> 8;  w0 |= w0 >> 14;
  w1 |= w1 >> 2;  w1 |= w1 >> 4;  w1 |= w1 >> 8;  w1 |= w1 >> 14;
  w2 |= w2 >> 2;  w2 |= w2 >> 4;  w2 |= w2 >> 8;  w2 |= w2 >> 14;
  w3 |= w3 >> 2;  w3 |= w3 >> 4;  w3 |= w3 >> 8;  w3 |= w3 >> 14;

  double lsum = 0.0;
  unsigned lcnt = 0;
#define CONSUME(G0, G1, q)                                                  \
  if (outl) {                                                               \
    _Pragma("unroll") for (int o = 0; o < 4; ++o) {                         \
      const int ro = 4 * (q) + o;                                           \
      const unsigned b0 = (unsigned)(w0 >> (2 * ro)) & 3u;                  \
      const unsigned b1 = (unsigned)(w1 >> (2 * ro)) & 3u;                  \
      const unsigned b2 = (unsigned)(w2 >> (2 * ro)) & 3u;                  \
      const unsigned b3 = (unsigned)(w3 >> (2 * ro)) & 3u;                  \
      const unsigned q0 = (cp0 >> (2 * ro)) & 3u;                           \
      const unsigned q1 = (cp1 >> (2 * ro)) & 3u;                           \
      const unsigned q2 = (cp2 >> (2 * ro)) & 3u;                           \
      const unsigned q3 = (cp3 >> (2 * ro)) & 3u;                           \
      const float4 a = G0[o], c = G1[o];                                    \
      const bool k0 = (b0 == 3u) && !(q0 & 2u);                             \
      const bool k1 = (b1 == 3u) && !(q1 & 2u);                             \
      const bool k2 = (b2 == 3u) && !(q2 & 2u);                             \
      const bool k3 = (b3 == 3u) && !(q3 & 2u);                             \
      lsum += k0 ? (double)((q0 & 1u) ? c.x : a.x) : 0.0;                   \
      lsum += k1 ? (double)((q1 & 1u) ? c.y : a.y) : 0.0;                   \
      lsum += k2 ? (double)((q2 & 1u) ? c.z : a.z) : 0.0;                   \
      lsum += k3 ? (double)((q3 & 1u) ? c.w : a.w) : 0.0;                   \
      lcnt += (unsigned)k0 + k1 + k2 + k3;                                  \
    }                                                                       \
  }

  // ---- phase 5: 4-quarter software pipeline; sched_barrier(0) fences
  //      prevent the scheduler hoisting issue(i+2) above consume(i), so at
  //      most 2 quarters (64 VGPR) of logits are ever live ----
  ISSUE(qb0, qb1, 1)
  CONSUME(qa0, qa1, 0)
  __builtin_amdgcn_sched_barrier(0);
  ISSUE(qa0, qa1, 2)
  CONSUME(qb0, qb1, 1)
  __builtin_amdgcn_sched_barrier(0);
  ISSUE(qb0, qb1, 3)
  CONSUME(qa0, qa1, 2)
  __builtin_amdgcn_sched_barrier(0);
  CONSUME(qb0, qb1, 3)
#undef ISSUE
#undef CONSUME

  // ---- wave reduction -> one double2 per block (no LDS, no barrier) ----
#pragma unroll
  for (int off = 32; off > 0; off >>= 1) {
    lsum += __shfl_down(lsum, off, 64);
    lcnt += __shfl_down(lcnt, off, 64);
  }
  if (lane == 0) partials[bid] = make_double2(lsum, (double)lcnt);
}

extern "C" __global__ __launch_bounds__(1024)
void boundary_loss_final(const double2* __restrict__ partials,
                         float* __restrict__ out)
{
  __shared__ double red_s[16];
  __shared__ double red_c[16];
  const int tid = threadIdx.x;
  double s = 0.0, c = 0.0;
  for (int i = tid; i < NBLK; i += 1024) {
    const double2 p = partials[i];
    s += p.x;
    c += p.y;
  }
#pragma unroll
  for (int off = 32; off > 0; off >>= 1) {
    s += __shfl_down(s, off, 64);
    c += __shfl_down(c, off, 64);
  }
  const int wave = tid >> 6;
  if ((tid & 63) == 0) { red_s[wave] = s; red_c[wave] = c; }
  __syncthreads();
  if (tid == 0) {
    double ts = 0.0, tc = 0.0;
#pragma unroll
    for (int i = 0; i < 16; ++i) { ts += red_s[i]; tc += red_c[i]; }
    if (tc < 1.0) tc = 1.0;
    out[0] = (float)(-ts / tc);
  }
}

extern "C" void kernel_launch(void* const* d_in, const int* in_sizes, int n_in,
                              void* d_out, int out_size, void* d_ws, size_t ws_size,
                              hipStream_t stream)
{
  const float* logits = (const float*)d_in[0];
  const int* labels = (const int*)d_in[1];
  float* out = (float*)d_out;
  double2* partials = (double2*)d_ws;  // NBLK*16 B = 61,440 B; every slot
                                       // written by main -> no init needed.

  boundary_loss_main<<<dim3(NBLK), 64, 0, stream>>>(logits, labels, partials);
  boundary_loss_final<<<1, 1024, 0, stream>>>(partials, out);
}